// Round 1
// baseline (102.897 us; speedup 1.0000x reference)
//
#include <hip/hip_runtime.h>
#include <math.h>

// PhiCell hysteresis scan: s' = max(x-0.5, min(x+0.5, s)) ; output o_t = s_t.
// Parallelized as an associative scan over (lo,hi) clamp operators.

#define T_ELEMS 8388608
#define BLOCK   256
#define EPT     32                    // elements per thread
#define EPB     (BLOCK * EPT)         // 8192 elements per block
#define NBLK    (T_ELEMS / EPB)       // 1024 blocks

struct Op { float lo, hi; };

// Apply operator a first, then b:  result(s) = b(a(s))
__device__ __forceinline__ Op combine(Op a, Op b) {
    Op r;
    r.lo = fmaxf(b.lo, fminf(b.hi, a.lo));
    r.hi = fminf(b.hi, a.hi);
    return r;
}

__device__ __forceinline__ float apply_op(Op o, float s) {
    return fmaxf(o.lo, fminf(o.hi, s));
}

__device__ __forceinline__ void fold_elem(Op& t, float e) {
    // t = combine(t, elem_op(e)) where elem_op = (e-0.5, e+0.5)
    float elo = e - 0.5f, ehi = e + 0.5f;
    t.lo = fmaxf(elo, fminf(ehi, t.lo));
    t.hi = fminf(ehi, t.hi);
}

// ---------------- phase 1: per-block operator totals ----------------
__global__ __launch_bounds__(BLOCK) void phase1(const float* __restrict__ x,
                                                const float* __restrict__ w,
                                                float2* __restrict__ blkTot) {
    __shared__ Op lds[BLOCK];
    const float wv = w[0];
    const int tid = threadIdx.x;
    const size_t base = ((size_t)blockIdx.x * BLOCK + tid) * EPT;
    const float4* xv = reinterpret_cast<const float4*>(x + base);

    Op t = { -__builtin_inff(), __builtin_inff() };
#pragma unroll
    for (int j = 0; j < EPT / 4; ++j) {
        float4 v = xv[j];
        fold_elem(t, v.x * wv);
        fold_elem(t, v.y * wv);
        fold_elem(t, v.z * wv);
        fold_elem(t, v.w * wv);
    }

    lds[tid] = t;
    __syncthreads();
    // ordered tree reduction (non-commutative but associative)
#pragma unroll
    for (int off = 1; off < BLOCK; off <<= 1) {
        if ((tid & (2 * off - 1)) == 0) {
            lds[tid] = combine(lds[tid], lds[tid + off]);
        }
        __syncthreads();
    }
    if (tid == 0) {
        blkTot[blockIdx.x] = make_float2(lds[0].lo, lds[0].hi);
    }
}

// ---------------- phase 2: scan block totals (one wave) ----------------
__global__ __launch_bounds__(64) void phase2(const float2* __restrict__ blkTot,
                                             const float* __restrict__ state0,
                                             float* __restrict__ blkStart,
                                             float* __restrict__ finalOut) {
    const int lane = threadIdx.x;          // one wave of 64 lanes, 16 blocks each
    const int PER = NBLK / 64;             // 16
    const float s0 = state0[0];

    // lane-local sequential composition of its 16 block totals
    Op t = { -__builtin_inff(), __builtin_inff() };
    Op tots[PER];
#pragma unroll
    for (int j = 0; j < PER; ++j) {
        float2 bt = blkTot[lane * PER + j];
        Op o = { bt.x, bt.y };
        tots[j] = o;
        t = combine(t, o);
    }

    // wave inclusive scan (shfl_up), non-commutative associative
    float plo = t.lo, phi_ = t.hi;
#pragma unroll
    for (int off = 1; off < 64; off <<= 1) {
        float nlo = __shfl_up(plo, off);
        float nhi = __shfl_up(phi_, off);
        if (lane >= off) {
            // neighbor (earlier) first, mine second
            float newlo = fmaxf(plo, fminf(phi_, nlo));
            float newhi = fminf(phi_, nhi);
            plo = newlo; phi_ = newhi;
        }
    }
    // exclusive
    float elo = __shfl_up(plo, 1);
    float ehi = __shfl_up(phi_, 1);
    if (lane == 0) { elo = -__builtin_inff(); ehi = __builtin_inff(); }

    float s = fmaxf(elo, fminf(ehi, s0));
#pragma unroll
    for (int j = 0; j < PER; ++j) {
        blkStart[lane * PER + j] = s;
        s = apply_op(tots[j], s);
    }
    if (lane == 63) {
        finalOut[0] = s;   // final state = d_out[T]
    }
}

// ---------------- phase 3: outputs ----------------
__global__ __launch_bounds__(BLOCK) void phase3(const float* __restrict__ x,
                                                const float* __restrict__ w,
                                                const float* __restrict__ blkStart,
                                                float* __restrict__ out) {
    __shared__ Op lds[BLOCK];
    const float wv = w[0];
    const int tid = threadIdx.x;
    const size_t base = ((size_t)blockIdx.x * BLOCK + tid) * EPT;
    const float4* xv = reinterpret_cast<const float4*>(x + base);

    // load and scale into registers; compute thread total
    float4 xr[EPT / 4];
    Op t = { -__builtin_inff(), __builtin_inff() };
#pragma unroll
    for (int j = 0; j < EPT / 4; ++j) {
        float4 v = xv[j];
        v.x *= wv; v.y *= wv; v.z *= wv; v.w *= wv;
        xr[j] = v;
        fold_elem(t, v.x);
        fold_elem(t, v.y);
        fold_elem(t, v.z);
        fold_elem(t, v.w);
    }

    // Hillis-Steele inclusive scan across the block
    lds[tid] = t;
    __syncthreads();
#pragma unroll
    for (int off = 1; off < BLOCK; off <<= 1) {
        Op cur = lds[tid];
        Op prev;
        bool act = (tid >= off);
        if (act) prev = lds[tid - off];
        __syncthreads();
        if (act) cur = combine(prev, cur);
        lds[tid] = cur;
        __syncthreads();
    }

    Op excl;
    if (tid == 0) {
        excl.lo = -__builtin_inff(); excl.hi = __builtin_inff();
    } else {
        excl = lds[tid - 1];
    }

    float s = blkStart[blockIdx.x];
    s = apply_op(excl, s);

    float4* ov = reinterpret_cast<float4*>(out + base);
#pragma unroll
    for (int j = 0; j < EPT / 4; ++j) {
        float4 v = xr[j];
        float4 o;
        s = fmaxf(v.x - 0.5f, fminf(v.x + 0.5f, s)); o.x = s;
        s = fmaxf(v.y - 0.5f, fminf(v.y + 0.5f, s)); o.y = s;
        s = fmaxf(v.z - 0.5f, fminf(v.z + 0.5f, s)); o.z = s;
        s = fmaxf(v.w - 0.5f, fminf(v.w + 0.5f, s)); o.w = s;
        ov[j] = o;
    }
}

extern "C" void kernel_launch(void* const* d_in, const int* in_sizes, int n_in,
                              void* d_out, int out_size, void* d_ws, size_t ws_size,
                              hipStream_t stream) {
    const float* x  = (const float*)d_in[0];   // (1, T) f32
    const float* w  = (const float*)d_in[1];   // (1, 1) f32
    const float* s0 = (const float*)d_in[2];   // (1, 1) f32
    float* out = (float*)d_out;                // [T outputs | final state]

    float2* blkTot   = (float2*)d_ws;                              // NBLK float2
    float*  blkStart = (float*)((char*)d_ws + NBLK * sizeof(float2)); // NBLK float

    phase1<<<NBLK, BLOCK, 0, stream>>>(x, w, blkTot);
    phase2<<<1, 64, 0, stream>>>(blkTot, s0, blkStart, out + T_ELEMS);
    phase3<<<NBLK, BLOCK, 0, stream>>>(x, w, blkStart, out);
}

// Round 3
// 102.614 us; speedup vs baseline: 1.0028x; 1.0028x over previous
//
#include <hip/hip_runtime.h>
#include <math.h>

// PhiCell hysteresis scan: s' = max(x-0.5, min(x+0.5, s)) ; output o_t = s_t.
// Parallelized as an associative scan over (lo,hi) clamp operators.
// R2 (resubmit after infra timeout): EPT=4 for perfect coalescing; wave shfl scans.

#define T_ELEMS 8388608
#define BLOCK   256
#define EPT     4                     // one float4 per thread -> coalesced
#define EPB     (BLOCK * EPT)         // 1024 elements per block
#define NBLK    (T_ELEMS / EPB)       // 8192 blocks
#define P2T     256
#define P2PER   (NBLK / P2T)          // 32 block-totals per phase2 thread

#define NEG_INF (-__builtin_inff())
#define POS_INF (__builtin_inff())

struct Op { float lo, hi; };

// Apply operator a first, then b:  result(s) = b(a(s))
__device__ __forceinline__ Op combine(Op a, Op b) {
    Op r;
    r.lo = fmaxf(b.lo, fminf(b.hi, a.lo));
    r.hi = fminf(b.hi, a.hi);
    return r;
}

__device__ __forceinline__ float apply_op(Op o, float s) {
    return fmaxf(o.lo, fminf(o.hi, s));
}

__device__ __forceinline__ void fold_elem(Op& t, float e) {
    float elo = e - 0.5f, ehi = e + 0.5f;
    t.lo = fmaxf(elo, fminf(ehi, t.lo));
    t.hi = fminf(ehi, t.hi);
}

// Thread's 4-element operator from a scaled float4 (time order x,y,z,w)
__device__ __forceinline__ Op thread_op(float4 v) {
    Op t = { v.x - 0.5f, v.x + 0.5f };
    fold_elem(t, v.y);
    fold_elem(t, v.z);
    fold_elem(t, v.w);
    return t;
}

// Ordered wave-inclusive scan (lane order = time order; associative, NOT commutative)
__device__ __forceinline__ Op wave_incl_scan(Op t, int lane) {
#pragma unroll
    for (int off = 1; off < 64; off <<= 1) {
        float nlo = __shfl_up(t.lo, off);
        float nhi = __shfl_up(t.hi, off);
        if (lane >= off) {
            Op prev = { nlo, nhi };
            t = combine(prev, t);
        }
    }
    return t;
}

// Block-exclusive operator for this thread, given its inclusive wave-scan result.
// lds_wt must have >= nwaves entries; call is block-collective.
__device__ __forceinline__ Op block_excl_from_incl(Op incl, int lane, int wid, Op* lds_wt) {
    if (lane == 63) lds_wt[wid] = incl;
    __syncthreads();
    Op wpre = { NEG_INF, POS_INF };
    for (int k = 0; k < wid; ++k) wpre = combine(wpre, lds_wt[k]);  // wid <= 3, wave-uniform
    float elo = __shfl_up(incl.lo, 1);
    float ehi = __shfl_up(incl.hi, 1);
    Op excl;
    if (lane == 0) { excl.lo = NEG_INF; excl.hi = POS_INF; }
    else           { excl.lo = elo;     excl.hi = ehi;     }
    return combine(wpre, excl);
}

// ---------------- phase 1: per-block operator totals ----------------
__global__ __launch_bounds__(BLOCK) void phase1(const float* __restrict__ x,
                                                const float* __restrict__ w,
                                                float2* __restrict__ blkTot) {
    __shared__ Op wt[BLOCK / 64];
    const float wv = w[0];
    const int tid = threadIdx.x;
    const size_t base = (size_t)blockIdx.x * EPB + (size_t)tid * EPT;
    float4 v = *reinterpret_cast<const float4*>(x + base);
    v.x *= wv; v.y *= wv; v.z *= wv; v.w *= wv;
    Op t = thread_op(v);

    // ordered wave reduction: combine(t[l], t[l+off]) keeps time order
#pragma unroll
    for (int off = 1; off < 64; off <<= 1) {
        float nlo = __shfl_down(t.lo, off);
        float nhi = __shfl_down(t.hi, off);
        Op nb = { nlo, nhi };
        t = combine(t, nb);
    }
    if ((tid & 63) == 0) wt[tid >> 6] = t;
    __syncthreads();
    if (tid == 0) {
        Op b = wt[0];
#pragma unroll
        for (int k = 1; k < BLOCK / 64; ++k) b = combine(b, wt[k]);
        blkTot[blockIdx.x] = make_float2(b.lo, b.hi);
    }
}

// ---------------- phase 2: scan 8192 block totals (one block) ----------------
__global__ __launch_bounds__(P2T) void phase2(const float2* __restrict__ blkTot,
                                              const float* __restrict__ state0,
                                              float* __restrict__ blkStart,
                                              float* __restrict__ finalOut) {
    __shared__ Op wt[P2T / 64];
    const int tid = threadIdx.x;
    const int lane = tid & 63, wid = tid >> 6;

    // sequential fold of this thread's 32 contiguous block totals
    Op t = { NEG_INF, POS_INF };
#pragma unroll 4
    for (int j = 0; j < P2PER; ++j) {
        float2 b = blkTot[tid * P2PER + j];
        Op o = { b.x, b.y };
        t = combine(t, o);
    }

    Op incl = wave_incl_scan(t, lane);
    Op myex = block_excl_from_incl(incl, lane, wid, wt);

    float s = apply_op(myex, state0[0]);
#pragma unroll 4
    for (int j = 0; j < P2PER; ++j) {
        blkStart[tid * P2PER + j] = s;
        float2 b = blkTot[tid * P2PER + j];   // L1-hot re-read, avoids 64 regs
        Op o = { b.x, b.y };
        s = apply_op(o, s);
    }
    if (tid == P2T - 1) finalOut[0] = s;      // final state = d_out[T]
}

// ---------------- phase 3: outputs ----------------
__global__ __launch_bounds__(BLOCK) void phase3(const float* __restrict__ x,
                                                const float* __restrict__ w,
                                                const float* __restrict__ blkStart,
                                                float* __restrict__ out) {
    __shared__ Op wt[BLOCK / 64];
    const float wv = w[0];
    const int tid = threadIdx.x;
    const int lane = tid & 63, wid = tid >> 6;
    const size_t base = (size_t)blockIdx.x * EPB + (size_t)tid * EPT;
    float4 v = *reinterpret_cast<const float4*>(x + base);
    v.x *= wv; v.y *= wv; v.z *= wv; v.w *= wv;

    Op t = thread_op(v);
    Op incl = wave_incl_scan(t, lane);
    Op myex = block_excl_from_incl(incl, lane, wid, wt);

    float s = apply_op(myex, blkStart[blockIdx.x]);

    float4 o;
    s = fmaxf(v.x - 0.5f, fminf(v.x + 0.5f, s)); o.x = s;
    s = fmaxf(v.y - 0.5f, fminf(v.y + 0.5f, s)); o.y = s;
    s = fmaxf(v.z - 0.5f, fminf(v.z + 0.5f, s)); o.z = s;
    s = fmaxf(v.w - 0.5f, fminf(v.w + 0.5f, s)); o.w = s;
    *reinterpret_cast<float4*>(out + base) = o;
}

extern "C" void kernel_launch(void* const* d_in, const int* in_sizes, int n_in,
                              void* d_out, int out_size, void* d_ws, size_t ws_size,
                              hipStream_t stream) {
    const float* x  = (const float*)d_in[0];   // (1, T) f32
    const float* w  = (const float*)d_in[1];   // (1, 1) f32
    const float* s0 = (const float*)d_in[2];   // (1, 1) f32
    float* out = (float*)d_out;                // [T outputs | final state]

    float2* blkTot   = (float2*)d_ws;                                 // NBLK float2 (64 KB)
    float*  blkStart = (float*)((char*)d_ws + NBLK * sizeof(float2)); // NBLK float  (32 KB)

    phase1<<<NBLK, BLOCK, 0, stream>>>(x, w, blkTot);
    phase2<<<1, P2T, 0, stream>>>(blkTot, s0, blkStart, out + T_ELEMS);
    phase3<<<NBLK, BLOCK, 0, stream>>>(x, w, blkStart, out);
}

// Round 7
// 92.344 us; speedup vs baseline: 1.1143x; 1.1112x over previous
//
#include <hip/hip_runtime.h>
#include <math.h>

// PhiCell hysteresis scan: s' = max(x-0.5, min(x+0.5, s)); output o_t = s_t.
// Associative scan over (lo,hi) clamp operators.
// R7: 2 kernels, NO inter-block sync. K1: per-block aggregates. K2: every
// block folds its own prefix from agg[] (L2-hot), re-reads x (L3-hot), applies.
// No atomics / barriers / co-residency assumptions. Verified R5 transpose.

#define T_ELEMS 8388608
#define NEG_INF (-__builtin_inff())
#define POS_INF (__builtin_inff())

#define BLOCK   256
#define WAVES   4
#define F4T     8                         // float4 per thread (32 floats)
#define F4W     (64 * F4T)                // 512 float4 per wave region
#define F4B     (BLOCK * F4T)             // 2048 float4 per block
#define EPB     (F4B * 4)                 // 8192 floats per block
#define NBLK    (T_ELEMS / EPB)           // 1024
#define APT     (NBLK / BLOCK)            // 4 agg entries per thread in K2

struct Op { float lo, hi; };

// Apply operator a first, then b:  result(s) = b(a(s))
__device__ __forceinline__ Op combine(Op a, Op b) {
    Op r;
    r.lo = fmaxf(b.lo, fminf(b.hi, a.lo));
    r.hi = fminf(b.hi, a.hi);
    return r;
}
__device__ __forceinline__ float apply_op(Op o, float s) {
    return fmaxf(o.lo, fminf(o.hi, s));
}
__device__ __forceinline__ void fold_elem(Op& t, float e) {
    float elo = e - 0.5f, ehi = e + 0.5f;
    t.lo = fmaxf(elo, fminf(ehi, t.lo));
    t.hi = fminf(ehi, t.hi);
}
__device__ __forceinline__ void fold4(Op& t, float4 v) {
    fold_elem(t, v.x); fold_elem(t, v.y); fold_elem(t, v.z); fold_elem(t, v.w);
}
// XOR swizzle on float4 index within a 512-float4 wave region (verified R5).
__device__ __forceinline__ int swz(int idx) { return idx ^ ((idx >> 3) & 7); }

// Ordered wave-inclusive scan (lane order = time order).
__device__ __forceinline__ Op wave_incl_scan(Op t, int lane) {
#pragma unroll
    for (int off = 1; off < 64; off <<= 1) {
        float nlo = __shfl_up(t.lo, off);
        float nhi = __shfl_up(t.hi, off);
        if (lane >= off) {
            Op prev = { nlo, nhi };
            t = combine(prev, t);
        }
    }
    return t;
}
// Ordered wave reduction (result valid in lane 0).
__device__ __forceinline__ Op wave_reduce(Op t) {
#pragma unroll
    for (int off = 1; off < 64; off <<= 1) {
        Op nb;
        nb.lo = __shfl_down(t.lo, off);
        nb.hi = __shfl_down(t.hi, off);
        t = combine(t, nb);
    }
    return t;
}

// Load this wave's 512 float4 tile, scale, transpose via swizzled LDS so each
// thread holds 32 time-contiguous floats in v[0..7]. wbuf = 512-f4 wave region.
__device__ __forceinline__ void load_tile(const float4* __restrict__ xg,
                                          size_t wbase, int lane, float wv,
                                          float4* wbuf, float4 v[F4T]) {
#pragma unroll
    for (int j = 0; j < F4T; ++j) {
        float4 t = xg[wbase + j * 64 + lane];
        t.x *= wv; t.y *= wv; t.z *= wv; t.w *= wv;
        wbuf[swz(j * 64 + lane)] = t;
    }
#pragma unroll
    for (int k = 0; k < F4T; ++k)
        v[k] = wbuf[swz(lane * F4T + k)];
}

// ---------------- K1: per-block aggregate operators ----------------
__global__ __launch_bounds__(BLOCK) void k1_agg(const float* __restrict__ x,
                                                const float* __restrict__ w,
                                                float2* __restrict__ agg) {
    __shared__ float4 xbuf[WAVES * F4W];   // 32 KB
    __shared__ Op wt[WAVES];
    const int tid = threadIdx.x, lane = tid & 63, wid = tid >> 6;
    const int b = blockIdx.x;
    const float wv = w[0];

    float4* wbuf = xbuf + wid * F4W;
    const size_t wbase = (size_t)b * F4B + (size_t)wid * F4W;
    const float4* xg = reinterpret_cast<const float4*>(x);

    float4 v[F4T];
    load_tile(xg, wbase, lane, wv, wbuf, v);

    Op t = { v[0].x - 0.5f, v[0].x + 0.5f };
    fold_elem(t, v[0].y); fold_elem(t, v[0].z); fold_elem(t, v[0].w);
#pragma unroll
    for (int k = 1; k < F4T; ++k) fold4(t, v[k]);

    t = wave_reduce(t);
    if (lane == 0) wt[wid] = t;
    __syncthreads();
    if (tid == 0) {
        Op bt = wt[0];
#pragma unroll
        for (int k = 1; k < WAVES; ++k) bt = combine(bt, wt[k]);
        agg[b] = make_float2(bt.lo, bt.hi);
    }
}

// ---------------- K2: per-block prefix fold + apply + store ----------------
__global__ __launch_bounds__(BLOCK) void k2_apply(const float* __restrict__ x,
                                                  const float* __restrict__ w,
                                                  const float* __restrict__ s0,
                                                  const float2* __restrict__ agg,
                                                  float* __restrict__ out) {
    __shared__ float4 xbuf[WAVES * F4W];   // 32 KB
    __shared__ Op wtA[WAVES];              // per-wave inclusive totals (this block)
    __shared__ Op wtP[WAVES];              // prefix-fold partials
    const int tid = threadIdx.x, lane = tid & 63, wid = tid >> 6;
    const int b = blockIdx.x;
    const float wv = w[0];

    // ---- block-exclusive prefix E_b = ordered fold of agg[0..b-1] ----
    Op seg = { NEG_INF, POS_INF };
#pragma unroll
    for (int j = 0; j < APT; ++j) {
        int i = tid * APT + j;
        if (i < b) {
            float2 f = agg[i];
            Op o = { f.x, f.y };
            seg = combine(seg, o);
        }
    }
    seg = wave_reduce(seg);
    if (lane == 0) wtP[wid] = seg;

    // ---- load tile, thread ops, in-block scan ----
    float4* wbuf = xbuf + wid * F4W;
    const size_t wbase = (size_t)b * F4B + (size_t)wid * F4W;
    const float4* xg = reinterpret_cast<const float4*>(x);

    float4 v[F4T];
    load_tile(xg, wbase, lane, wv, wbuf, v);

    Op t = { v[0].x - 0.5f, v[0].x + 0.5f };
    fold_elem(t, v[0].y); fold_elem(t, v[0].z); fold_elem(t, v[0].w);
#pragma unroll
    for (int k = 1; k < F4T; ++k) fold4(t, v[k]);

    Op incl = wave_incl_scan(t, lane);
    if (lane == 63) wtA[wid] = incl;
    __syncthreads();

    Op Eb = wtP[0];
#pragma unroll
    for (int k = 1; k < WAVES; ++k) Eb = combine(Eb, wtP[k]);

    Op wpre = { NEG_INF, POS_INF };
    for (int k = 0; k < wid; ++k) wpre = combine(wpre, wtA[k]);
    float elo = __shfl_up(incl.lo, 1);
    float ehi = __shfl_up(incl.hi, 1);
    Op excl;
    if (lane == 0) { excl.lo = NEG_INF; excl.hi = POS_INF; }
    else           { excl.lo = elo;     excl.hi = ehi;     }

    float s = apply_op(Eb, s0[0]);            // state entering this block
    s = apply_op(combine(wpre, excl), s);     // state entering this thread

    // ---- apply 32 elems; store through the same transpose ----
    float4* og = reinterpret_cast<float4*>(out);
#pragma unroll
    for (int k = 0; k < F4T; ++k) {
        float4 e = v[k], o4;
        s = fmaxf(e.x - 0.5f, fminf(e.x + 0.5f, s)); o4.x = s;
        s = fmaxf(e.y - 0.5f, fminf(e.y + 0.5f, s)); o4.y = s;
        s = fmaxf(e.z - 0.5f, fminf(e.z + 0.5f, s)); o4.z = s;
        s = fmaxf(e.w - 0.5f, fminf(e.w + 0.5f, s)); o4.w = s;
        wbuf[swz(lane * F4T + k)] = o4;
    }
#pragma unroll
    for (int j = 0; j < F4T; ++j)
        og[wbase + j * 64 + lane] = wbuf[swz(j * 64 + lane)];

    if (b == NBLK - 1 && tid == BLOCK - 1)
        out[T_ELEMS] = s;                     // final state
}

extern "C" void kernel_launch(void* const* d_in, const int* in_sizes, int n_in,
                              void* d_out, int out_size, void* d_ws, size_t ws_size,
                              hipStream_t stream) {
    const float* x  = (const float*)d_in[0];   // (1, T) f32
    const float* w  = (const float*)d_in[1];   // (1, 1) f32
    const float* s0 = (const float*)d_in[2];   // (1, 1) f32
    float* out = (float*)d_out;                // [T outputs | final state]

    float2* agg = (float2*)d_ws;               // NBLK float2 (8 KB)

    k1_agg<<<NBLK, BLOCK, 0, stream>>>(x, w, agg);
    k2_apply<<<NBLK, BLOCK, 0, stream>>>(x, w, s0, agg, out);
}